// Round 8
// baseline (444.597 us; speedup 1.0000x reference)
//
#include <hip/hip_runtime.h>
#include <math.h>
#include <stdint.h>

#define B_ 32
#define C_ 32
#define H_ 16
#define V_ 8192
#define HW_ 256
#define NELEM (B_*C_*H_*H_)   // 262144
#define TBYTES 6208           // per 16-code tile: 3*2048 frag planes + 64 e2sq
#define ZPL 262144            // zb plane stride (elements)

typedef short bf16x8 __attribute__((ext_vector_type(8)));
typedef unsigned short u16x8 __attribute__((ext_vector_type(8)));
typedef float f32x4 __attribute__((ext_vector_type(4)));
typedef unsigned long long ull;

__device__ __forceinline__ unsigned int fkey(float f) {
    unsigned int u = __float_as_uint(f);
    return (u & 0x80000000u) ? ~u : (u | 0x80000000u);
}
__device__ __forceinline__ unsigned short f2bf(float x) {
    unsigned int u = __float_as_uint(x);
    unsigned int r = u + 0x7fffu + ((u >> 16) & 1u);
    return (unsigned short)(r >> 16);
}
__device__ __forceinline__ float bf2f(unsigned short h) {
    return __uint_as_float(((unsigned int)h) << 16);
}

// init f_rest/f_hat; build E-fragment blob (A-frag order, -2E bf16x3 + e2sq)
__global__ void __launch_bounds__(256) k_init(
    const float* __restrict__ f, const float* __restrict__ emb,
    float* __restrict__ f_rest, float* __restrict__ f_hat,
    char* __restrict__ blob, float* __restrict__ lossAcc)
{
    int i = blockIdx.x*256 + threadIdx.x;
    if (i < NELEM) { float v = f[i]; f_rest[i] = v; f_hat[i] = 0.f; }
    if (i < 512*64) {
        int t = i >> 6, l = i & 63;
        int row = t*16 + (l & 15);
        int k0 = (l >> 4) * 8;
        const float* er = emb + row*C_ + k0;
        u16x8 h0, h1, h2;
        #pragma unroll
        for (int j = 0; j < 8; ++j) {
            float x = -2.f * er[j];
            unsigned short b0 = f2bf(x);  float r1 = x - bf2f(b0);
            unsigned short b1 = f2bf(r1); float r2 = r1 - bf2f(b1);
            unsigned short b2 = f2bf(r2);
            h0[j] = b0; h1[j] = b1; h2[j] = b2;
        }
        char* tb = blob + (size_t)t*TBYTES;
        *(u16x8*)(tb +        l*16) = h0;
        *(u16x8*)(tb + 2048 + l*16) = h1;
        *(u16x8*)(tb + 4096 + l*16) = h2;
        if ((l >> 4) == 0) {
            const float4* e4 = (const float4*)(emb + row*C_);
            float s = 0.f;
            #pragma unroll
            for (int cc = 0; cc < 8; ++cc) {
                float4 ev = e4[cc];
                s += ev.x*ev.x + ev.y*ev.y + ev.z*ev.z + ev.w*ev.w;
            }
            *(float*)(tb + 6144 + (l & 15)*4) = s;
        }
    }
    if (i == 0) lossAcc[0] = 0.f;
}

// area pool (used only for scale 0, pn=1) -> zb bf16x3 planes; init best
__global__ void __launch_bounds__(256) k_pool(
    const float* __restrict__ f_rest, unsigned short* __restrict__ zb,
    ull* __restrict__ best, int pn, int N)
{
    int gid = blockIdx.x*256 + threadIdx.x;
    if (gid >= N*C_) return;
    int c = gid & 31;
    int n = gid >> 5;
    if (c == 0) best[n] = ~0ull;
    int pp = pn*pn;
    int b = n / pp;
    int rem = n - b*pp;
    int p = rem / pn;
    int q = rem - p*pn;
    int hs = (p*H_)/pn,  he = ((p+1)*H_ + pn-1)/pn;
    int ws = (q*H_)/pn,  we = ((q+1)*H_ + pn-1)/pn;
    const float* base = f_rest + ((size_t)(b*C_ + c))*HW_;
    float s = 0.f;
    for (int hh = hs; hh < he; ++hh)
        for (int ww = ws; ww < we; ++ww)
            s += base[hh*H_ + ww];
    float inv = (1.f/(float)(he-hs)) * (1.f/(float)(we-ws));
    float x = s * inv;
    unsigned short b0 = f2bf(x);  float r1 = x - bf2f(b0);
    unsigned short b1 = f2bf(r1); float r2 = r1 - bf2f(b1);
    unsigned short b2 = f2bf(r2);
    size_t o = (size_t)n*C_ + c;
    zb[o] = b0; zb[o + ZPL] = b1; zb[o + 2*ZPL] = b2;
}

// one query-tile distance step: 6 MFMA (bf16x3 split, s+t<=2) + running argmin
__device__ __forceinline__ void qstep(
    const bf16x8 a0, const bf16x8 a1, const bf16x8 a2, const f32x4 e2v,
    const bf16x8* Bf, int cbase, float& dmin, int& imin)
{
    f32x4 acc = e2v;
    acc = __builtin_amdgcn_mfma_f32_16x16x32_bf16(a0, Bf[0], acc, 0, 0, 0);
    acc = __builtin_amdgcn_mfma_f32_16x16x32_bf16(a1, Bf[0], acc, 0, 0, 0);
    acc = __builtin_amdgcn_mfma_f32_16x16x32_bf16(a0, Bf[1], acc, 0, 0, 0);
    acc = __builtin_amdgcn_mfma_f32_16x16x32_bf16(a2, Bf[0], acc, 0, 0, 0);
    acc = __builtin_amdgcn_mfma_f32_16x16x32_bf16(a1, Bf[1], acc, 0, 0, 0);
    acc = __builtin_amdgcn_mfma_f32_16x16x32_bf16(a0, Bf[2], acc, 0, 0, 0);
    float mt = fminf(fminf(acc.x, acc.y), fminf(acc.z, acc.w));
    if (mt < dmin) {
        dmin = mt;
        imin = cbase + ((acc.x==mt) ? 0 : (acc.y==mt) ? 1 : (acc.z==mt) ? 2 : 3);
    }
}

// MFMA VQ: wave = 4 query-tiles x V-chunk; A-frags read direct from global
// (L2-resident blob), register double-buffered; no LDS, no barriers.
__global__ void __launch_bounds__(256, 2) k_vqm(
    const char* __restrict__ blob, const unsigned short* __restrict__ zb,
    ull* __restrict__ best, int N, int lvs)
{
    int tid = threadIdx.x, lane = tid & 63, w = tid >> 6;
    int qtiles_total = N >> 4;
    int qb = blockIdx.x >> lvs;
    int vc = blockIdx.x & ((1 << lvs) - 1);
    int tiles = 512 >> lvs;
    int t0 = vc * tiles;
    int qt0 = qb*16 + w*4;
    int qr = lane & 15, kq = lane >> 4;

    bf16x8 Bf0[3], Bf1[3], Bf2[3], Bf3[3];
    int qv0, qv1, qv2, qv3;
    {
        int qtj;
        size_t o;
        qtj = qt0 + 0; qv0 = (qtj < qtiles_total);
        o = (size_t)((qv0 ? qtj : 0)*16 + qr)*C_ + kq*8;
        Bf0[0] = *(const bf16x8*)(zb + o);
        Bf0[1] = *(const bf16x8*)(zb + o + ZPL);
        Bf0[2] = *(const bf16x8*)(zb + o + 2*ZPL);
        qtj = qt0 + 1; qv1 = (qtj < qtiles_total);
        o = (size_t)((qv1 ? qtj : 0)*16 + qr)*C_ + kq*8;
        Bf1[0] = *(const bf16x8*)(zb + o);
        Bf1[1] = *(const bf16x8*)(zb + o + ZPL);
        Bf1[2] = *(const bf16x8*)(zb + o + 2*ZPL);
        qtj = qt0 + 2; qv2 = (qtj < qtiles_total);
        o = (size_t)((qv2 ? qtj : 0)*16 + qr)*C_ + kq*8;
        Bf2[0] = *(const bf16x8*)(zb + o);
        Bf2[1] = *(const bf16x8*)(zb + o + ZPL);
        Bf2[2] = *(const bf16x8*)(zb + o + 2*ZPL);
        qtj = qt0 + 3; qv3 = (qtj < qtiles_total);
        o = (size_t)((qv3 ? qtj : 0)*16 + qr)*C_ + kq*8;
        Bf3[0] = *(const bf16x8*)(zb + o);
        Bf3[1] = *(const bf16x8*)(zb + o + ZPL);
        Bf3[2] = *(const bf16x8*)(zb + o + 2*ZPL);
    }

    float dmin[4]; int imin[4];
    #pragma unroll
    for (int j = 0; j < 4; ++j) { dmin[j] = __builtin_inff(); imin[j] = 0; }

    const char* tb = blob + (size_t)t0*TBYTES;
    bf16x8 Xa0, Xa1, Xa2; f32x4 Xe;
    bf16x8 Ya0, Ya1, Ya2; f32x4 Ye;
    Xa0 = *(const bf16x8*)(tb +        lane*16);
    Xa1 = *(const bf16x8*)(tb + 2048 + lane*16);
    Xa2 = *(const bf16x8*)(tb + 4096 + lane*16);
    Xe  = *(const f32x4*)(tb + 6144 + kq*16);

    for (int tt = 0; tt < tiles; tt += 2) {
        const char* nb = tb + TBYTES;
        Ya0 = *(const bf16x8*)(nb +        lane*16);
        Ya1 = *(const bf16x8*)(nb + 2048 + lane*16);
        Ya2 = *(const bf16x8*)(nb + 4096 + lane*16);
        Ye  = *(const f32x4*)(nb + 6144 + kq*16);
        {
            int cbase = (t0 + tt)*16 + kq*4;
            qstep(Xa0, Xa1, Xa2, Xe, Bf0, cbase, dmin[0], imin[0]);
            qstep(Xa0, Xa1, Xa2, Xe, Bf1, cbase, dmin[1], imin[1]);
            qstep(Xa0, Xa1, Xa2, Xe, Bf2, cbase, dmin[2], imin[2]);
            qstep(Xa0, Xa1, Xa2, Xe, Bf3, cbase, dmin[3], imin[3]);
        }
        const char* nb2 = (tt + 2 < tiles) ? tb + 2*TBYTES : tb;
        Xa0 = *(const bf16x8*)(nb2 +        lane*16);
        Xa1 = *(const bf16x8*)(nb2 + 2048 + lane*16);
        Xa2 = *(const bf16x8*)(nb2 + 4096 + lane*16);
        Xe  = *(const f32x4*)(nb2 + 6144 + kq*16);
        {
            int cbase = (t0 + tt + 1)*16 + kq*4;
            qstep(Ya0, Ya1, Ya2, Ye, Bf0, cbase, dmin[0], imin[0]);
            qstep(Ya0, Ya1, Ya2, Ye, Bf1, cbase, dmin[1], imin[1]);
            qstep(Ya0, Ya1, Ya2, Ye, Bf2, cbase, dmin[2], imin[2]);
            qstep(Ya0, Ya1, Ya2, Ye, Bf3, cbase, dmin[3], imin[3]);
        }
        tb += 2*TBYTES;
    }

    int qvv[4] = {qv0, qv1, qv2, qv3};
    #pragma unroll
    for (int j = 0; j < 4; ++j) {
        ull key = ((ull)fkey(dmin[j]) << 32) | (unsigned int)imin[j];
        ull o1 = __shfl_xor(key, 16); key = o1 < key ? o1 : key;
        ull o2 = __shfl_xor(key, 32); key = o2 < key ? o2 : key;
        if (kq == 0 && qvv[j]) {
            int q = (qt0 + j)*16 + qr;
            atomicMin(best + q, key);
        }
    }
}

__device__ __forceinline__ void cubic_taps(int i, int pn, float* wt, int* col) {
    double src = ((double)i + 0.5) * ((double)pn / 16.0) - 0.5;
    double fl = floor(src);
    const double A = -0.75;
    #pragma unroll
    for (int k = 0; k < 4; ++k) {
        double j = fl - 1.0 + (double)k;
        double d = fabs(src - j);
        double w;
        if (d <= 1.0)      w = ((A+2.0)*d - (A+3.0))*d*d + 1.0;
        else if (d < 2.0)  w = ((A*d - 5.0*A)*d + 8.0*A)*d - 4.0*A;
        else               w = 0.0;
        wt[k] = (float)w;
        int jj = (int)j;
        col[k] = jj < 0 ? 0 : (jj > pn-1 ? pn-1 : jj);
    }
}

// bicubic upsample: thread = (c, px, bi); coalesced emb gather -> h_up global
__global__ void __launch_bounds__(256) k_up(
    const ull* __restrict__ best, const float* __restrict__ emb,
    float* __restrict__ h_up, int pn)
{
    int i = blockIdx.x*256 + threadIdx.x;
    int c  = i & 31;
    int px = (i >> 5) & 255;
    int bi = i >> 13;
    int h = px >> 4, w = px & 15;
    float wh[4]; int th[4];
    float wwt[4]; int tw[4];
    cubic_taps(h, pn, wh, th);
    cubic_taps(w, pn, wwt, tw);
    const ull* bptr = best + bi*pn*pn;
    float acc = 0.f;
    #pragma unroll
    for (int ii = 0; ii < 4; ++ii) {
        if (wh[ii] == 0.f) continue;
        #pragma unroll
        for (int j = 0; j < 4; ++j) {
            float wt = wh[ii]*wwt[j];
            if (wt == 0.f) continue;
            unsigned int idx = (unsigned int)(bptr[th[ii]*pn + tw[j]] & 0xffffffffull);
            acc = fmaf(wt, emb[(size_t)idx*C_ + c], acc);
        }
    }
    h_up[(size_t)bi*8192 + px*32 + c] = acc;
}

// conv3x3 + Phi blend from staged h_up; f_hat/f_rest update; loss;
// fused area-pool -> zb planes for next scale + init next best
__global__ void __launch_bounds__(256) k_conv(
    const float* __restrict__ h_up,
    const float* __restrict__ cw, const float* __restrict__ cb,
    const float* __restrict__ forig,
    float* __restrict__ f_hat, float* __restrict__ f_rest,
    float* __restrict__ lossAcc,
    int pn2, unsigned short* __restrict__ zb, ull* __restrict__ bestN)
{
    __shared__ float hup[16][16][33];
    __shared__ float red[4];
    int bi = blockIdx.x >> 3;
    int g  = blockIdx.x & 7;
    int tid = threadIdx.x;
    int h = tid >> 4, w = tid & 15;

    // stage h_up[bi] (8192 floats) -> hup, coalesced float4 reads
    const float4* src = (const float4*)(h_up + (size_t)bi*8192);
    #pragma unroll
    for (int cc = 0; cc < 8; ++cc) {
        int f4 = cc*256 + tid;
        float4 v = src[f4];
        int px = f4 >> 3, c0 = (f4 & 7)*4;
        hup[px >> 4][px & 15][c0+0] = v.x;
        hup[px >> 4][px & 15][c0+1] = v.y;
        hup[px >> 4][px & 15][c0+2] = v.z;
        hup[px >> 4][px & 15][c0+3] = v.w;
    }
    __syncthreads();

    int co0 = g*4;
    float o4[4];
    #pragma unroll
    for (int k = 0; k < 4; ++k) o4[k] = cb[co0+k];
    for (int ci = 0; ci < 32; ++ci) {
        float hv[9];
        #pragma unroll
        for (int dh = 0; dh < 3; ++dh) {
            int hh = h + dh - 1;
            #pragma unroll
            for (int dw = 0; dw < 3; ++dw) {
                int ww2 = w + dw - 1;
                bool ok = (hh >= 0) & (hh < 16) & (ww2 >= 0) & (ww2 < 16);
                hv[dh*3+dw] = ok ? hup[hh & 15][ww2 & 15][ci] : 0.f;
            }
        }
        #pragma unroll
        for (int k = 0; k < 4; ++k) {
            const float* wr = cw + ((size_t)(co0+k)*C_ + ci)*9;
            float s = 0.f;
            #pragma unroll
            for (int p2 = 0; p2 < 9; ++p2) s = fmaf(hv[p2], wr[p2], s);
            o4[k] += s;
        }
    }
    __syncthreads();   // all conv reads of hup complete

    float sq = 0.f;
    #pragma unroll
    for (int k = 0; k < 4; ++k) {
        float hv0 = hup[h][w][co0+k];
        float outv = 0.5f*hv0 + 0.5f*o4[k];
        size_t off = ((size_t)(bi*C_ + co0 + k))*HW_ + h*16 + w;
        float fh = f_hat[off] + outv;
        f_hat[off] = fh;
        float fr = f_rest[off] - outv;
        f_rest[off] = fr;
        hup[h][w][co0+k] = fr;          // stash new f_rest for fused pool
        float df = fh - forig[off];
        sq = fmaf(df, df, sq);
    }
    #pragma unroll
    for (int o2 = 32; o2 > 0; o2 >>= 1) sq += __shfl_down(sq, o2, 64);
    if ((tid & 63) == 0) red[tid >> 6] = sq;
    __syncthreads();
    if (tid == 0) atomicAdd(lossAcc, (red[0]+red[1])+(red[2]+red[3]));

    // fused area-pool for next scale
    if (pn2 > 0 && h < pn2 && w < pn2) {
        int hs = (h*H_)/pn2,  he2 = ((h+1)*H_ + pn2-1)/pn2;
        int ws2 = (w*H_)/pn2, we2 = ((w+1)*H_ + pn2-1)/pn2;
        float inv = (1.f/(float)(he2-hs)) * (1.f/(float)(we2-ws2));
        int n = bi*pn2*pn2 + h*pn2 + w;
        #pragma unroll
        for (int k = 0; k < 4; ++k) {
            float s = 0.f;
            for (int hh = hs; hh < he2; ++hh)
                for (int ww = ws2; ww < we2; ++ww)
                    s += hup[hh][ww][co0+k];
            float x = s * inv;
            unsigned short b0 = f2bf(x);  float r1 = x - bf2f(b0);
            unsigned short b1 = f2bf(r1); float r2 = r1 - bf2f(b1);
            unsigned short b2 = f2bf(r2);
            size_t o = (size_t)n*C_ + co0 + k;
            zb[o] = b0; zb[o + ZPL] = b1; zb[o + 2*ZPL] = b2;
        }
        if (g == 0) bestN[n] = ~0ull;
    }
}

__global__ void __launch_bounds__(256) k_final(
    const float* __restrict__ f_hat, const float* __restrict__ lossAcc,
    float* __restrict__ out)
{
    int i = blockIdx.x*256 + threadIdx.x;
    if (i < NELEM) out[i] = f_hat[i];
    if (i == 0) out[NELEM] = lossAcc[0] * 1.25f / ((float)NELEM * 10.f);
}

extern "C" void kernel_launch(void* const* d_in, const int* in_sizes, int n_in,
                              void* d_out, int out_size, void* d_ws, size_t ws_size,
                              hipStream_t stream)
{
    const float* f   = (const float*)d_in[0];
    const float* emb = (const float*)d_in[1];
    const float* cw  = (const float*)d_in[2];
    const float* cb  = (const float*)d_in[3];
    float* out = (float*)d_out;
    char* ws = (char*)d_ws;
    ull*   best0  = (ull*)ws;                                  // 64 KB
    ull*   best1  = (ull*)(ws + 65536);                        // 64 KB
    float* f_rest = (float*)(ws + 131072);                     // 1 MB
    float* f_hat  = (float*)(ws + 131072 + 1048576);           // 1 MB
    unsigned short* zb = (unsigned short*)(ws + 2228224);      // 1.5 MB
    char*  blob   = ws + 3801088;                              // 512*6208 B
    float* lossAcc = (float*)(ws + 6979584);
    float* h_up   = (float*)(ws + 7340032);                    // 1 MB

    // Replicate PHI_IDX with numpy-linspace double semantics (no FP contraction)
    volatile double a   = 1.0/3.0/4.0;
    volatile double bb  = 1.0 - a;
    volatile double stp = (bb - a) / 3.0;
    double ticks[4];
    for (int i = 0; i < 4; ++i) { volatile double m = (double)i * stp; ticks[i] = m + a; }
    ticks[3] = bb;
    static const int pns[10] = {1,2,3,4,5,6,8,10,13,16};
    int phi_idx[10];
    for (int si = 0; si < 10; ++si) {
        volatile double x = (double)si / 9.0;
        int bi = 0; double bd = fabs(ticks[0] - x);
        for (int k = 1; k < 4; ++k) {
            double d = fabs(ticks[k] - x);
            if (d < bd) { bd = d; bi = k; }
        }
        phi_idx[si] = bi;
    }

    k_init<<<1024, 256, 0, stream>>>(f, emb, f_rest, f_hat, blob, lossAcc);
    k_pool<<<4, 256, 0, stream>>>(f_rest, zb, best0, 1, 32);

    static const int lvss[10] = {6,6,6,6,6,6,6,5,5,4};
    for (int si = 0; si < 10; ++si) {
        int pn = pns[si];
        int N = B_*pn*pn;
        int qtiles = N >> 4;
        int qblocks = (qtiles + 15)/16;
        int lvs = lvss[si];
        ull* bcur  = (si & 1) ? best1 : best0;
        ull* bnext = (si & 1) ? best0 : best1;
        k_vqm<<<qblocks << lvs, 256, 0, stream>>>(blob, zb, bcur, N, lvs);
        k_up<<<1024, 256, 0, stream>>>(bcur, emb, h_up, pn);
        const float* cwp = cw + (size_t)phi_idx[si]*C_*C_*9;
        const float* cbp = cb + (size_t)phi_idx[si]*C_;
        int pn2 = (si < 9) ? pns[si+1] : 0;
        k_conv<<<B_*8, 256, 0, stream>>>(h_up, cwp, cbp, f, f_hat, f_rest,
                                         lossAcc, pn2, zb, bnext);
    }
    k_final<<<1024, 256, 0, stream>>>(f_hat, lossAcc, out);
}